// Round 10
// baseline (284.632 us; speedup 1.0000x reference)
//
#include <hip/hip_runtime.h>
#include <math.h>

#define B_   8
#define S_   512
#define D_   768
#define H_   12
#define DH_  64
#define NTOK (B_*S_)        // 4096
#define D2_  (2*D_)         // 1536
#define D3_  (3*D_)         // 2304
#define ND_  ((size_t)NTOK * D_)      // 3145728
#define WSZ_ ((size_t)D_ * D_)        // 589824
#define FSZ_ ((size_t)D2_ * D_)       // 1179648

typedef unsigned short ushortT;
typedef short bf16x8 __attribute__((ext_vector_type(8)));
typedef float f32x4  __attribute__((ext_vector_type(4)));
typedef unsigned int u32;

#define QSCL 0.1803368801111204f   // 0.125 * log2(e): folded into Wq/bq/Wqm/bqm

__device__ __forceinline__ unsigned short f2bf(float f) {
    unsigned int x = __float_as_uint(f);
    unsigned int lsb = (x >> 16) & 1u;
    x += 0x7fffu + lsb;            // RNE
    return (unsigned short)(x >> 16);
}
__device__ __forceinline__ u32 pkbf(float a, float b) {
    u32 ua = (__float_as_uint(a) + 0x8000u) >> 16;
    u32 ub = (__float_as_uint(b) + 0x8000u) & 0xffff0000u;
    return ua | ub;
}

#if __has_builtin(__builtin_amdgcn_exp2f)
#define EXP2(x) __builtin_amdgcn_exp2f(x)
#else
#define EXP2(x) exp2f(x)
#endif

__device__ __forceinline__ void ld_g2l16(const ushortT* g, ushortT* l) {
    __builtin_amdgcn_global_load_lds(
        (const __attribute__((address_space(1))) u32*)g,
        (__attribute__((address_space(3))) u32*)l, 16, 0, 0);
}

// ================= PREP: converts + transposes + bco init + stacked bias ==========
#define PREP_NBLK 13080
struct PrepJob {
    const float *hs, *mol, *Wfc, *Wfcm;
    ushortT *hsb, *molb, *Wfcb, *Wfcmb;
    const float* tw_in[8]; ushortT* tw_out[8]; float tw_scl[8];
    const float *bo, *bom;
    const float *bq, *bk, *bv, *bqm, *bkm, *bvm;
    float *bcoP, *bcoM, *bqkvP, *bqkvM;
};
__global__ __launch_bounds__(256) void prep_k(PrepJob pj)
{
    __shared__ float t[32][33];
    const int bx = blockIdx.x;
    const int tid = threadIdx.x;

    if (bx < 8448) {                        // ---- converts ----
        const float* in; ushortT* out; int base;
        if (bx < 3072)      { in = pj.hs;   out = pj.hsb;   base = 0; }
        else if (bx < 6144) { in = pj.mol;  out = pj.molb;  base = 3072; }
        else if (bx < 7296) { in = pj.Wfc;  out = pj.Wfcb;  base = 6144; }
        else                { in = pj.Wfcm; out = pj.Wfcmb; base = 7296; }
        size_t i = ((size_t)(bx - base) * 256 + tid) * 4;
        float4 f = *(const float4*)(in + i);
        ushort4 u;
        u.x = f2bf(f.x); u.y = f2bf(f.y); u.z = f2bf(f.z); u.w = f2bf(f.w);
        *(ushort4*)(out + i) = u;
    } else if (bx < 13056) {                // ---- weight transposes ----
        int sub = bx - 8448;
        int z = sub / 576, r = sub - z * 576;
        int by = r / 24, bxx = r - by * 24;
        const float* __restrict__ in = pj.tw_in[z];
        ushortT* __restrict__ out = pj.tw_out[z];
        const float scl = pj.tw_scl[z];
        const int r0 = by * 32, c0 = bxx * 32;
        const int x = tid & 31, y = tid >> 5;
        #pragma unroll
        for (int i = 0; i < 4; ++i)
            t[y + 8 * i][x] = in[(size_t)(r0 + y + 8 * i) * D_ + c0 + x];
        __syncthreads();
        #pragma unroll
        for (int i = 0; i < 4; ++i)
            out[(size_t)(c0 + y + 8 * i) * D_ + r0 + x] = f2bf(t[x][y + 8 * i] * scl);
    } else if (bx < 13062) {                // ---- bco init ----
        int i = bx - 13056;                  // 0..5
        int zb = i / 3;
        int n = (i - zb * 3) * 256 + tid;
        if (zb == 0) pj.bcoP[n] = pj.bo[n];
        else         pj.bcoM[n] = pj.bom[n];
    } else {                                // ---- bqkv (stacked, pre-scaled) ----
        int i = bx - 13062;                  // 0..17
        int z = i / 9;
        int n = (i - z * 9) * 256 + tid;     // 0..2303
        int seg = n / D_, off = n - seg * D_;
        float v;
        if (z == 0)
            v = (seg == 0) ? pj.bq[off] * QSCL : (seg == 1 ? pj.bk[off] : pj.bv[off]);
        else
            v = (seg == 0) ? pj.bqm[off] * QSCL : (seg == 1 ? pj.bkm[off] : pj.bvm[off]);
        (z == 0 ? pj.bqkvP : pj.bqkvM)[n] = v;
    }
}

// ================= flat batched MFMA GEMM + trailing bco-fold blocks ================
// 128x128 tile, BK=64 (32 KB LDS), XOR-swizzled (chunk ^= row&7).
// flags: 1 = fp32 out, 2 = bias, 4 = QKV-split epilogue, 8 = XCD-aware remap.
struct GJob {
    const ushortT* X;
    const ushortT* Wt;
    const float*   bias;    // fp32, pre-scaled
    void*          Y;
    ushortT*       Yv;      // V-transpose target [bh][d][s] (flags&4)
    int            nx;      // N/128
    int            nblk;    // nx * M/128
    int            ldy;
    int            flags;
};
struct GJobs { GJob j[4]; };
struct FoldArgs { const float *bfc, *Wo, *bfcm, *Wom; float *bcoP, *bcoM; };

__global__ __launch_bounds__(256) void gemm_flat(GJobs gjs, FoldArgs fa, int K, int gemm_total)
{
    __shared__ __attribute__((aligned(16))) ushortT At[128 * 64];
    __shared__ __attribute__((aligned(16))) ushortT Bt[128 * 64];

    const int tid = threadIdx.x;
    int bx = blockIdx.x;

    if (bx >= gemm_total) {                 // ---- bco fold (32 blocks, 48-j chunks) ----
        int fi = bx - gemm_total;
        int zb = fi >> 4, chunk = fi & 15;
        const float* bf_ = zb ? fa.bfcm : fa.bfc;
        const float* W_  = zb ? fa.Wom : fa.Wo;
        float* o_ = zb ? fa.bcoM : fa.bcoP;
        float s0 = 0.f, s1 = 0.f, s2 = 0.f;
        const int j0 = chunk * 48;
        #pragma unroll 4
        for (int j = j0; j < j0 + 48; ++j) {
            float bv = bf_[j];
            const float* row = W_ + (size_t)j * D_;
            s0 += bv * row[tid];
            s1 += bv * row[tid + 256];
            s2 += bv * row[tid + 512];
        }
        atomicAdd(&o_[tid], s0);
        atomicAdd(&o_[tid + 256], s1);
        atomicAdd(&o_[tid + 512], s2);
        return;
    }

    int ji = 0;
    while (bx >= gjs.j[ji].nblk) { bx -= gjs.j[ji].nblk; ++ji; }
    const ushortT* __restrict__ X  = gjs.j[ji].X;
    const ushortT* __restrict__ Wt = gjs.j[ji].Wt;
    const float* __restrict__ bias = gjs.j[ji].bias;
    void* Y        = gjs.j[ji].Y;
    ushortT* Yv    = gjs.j[ji].Yv;
    const int nx   = gjs.j[ji].nx;
    const int ldy  = gjs.j[ji].ldy;
    const int flags= gjs.j[ji].flags;

    int by, bxx;
    if (flags & 8) {
        // XCD-aware remap: consecutive blockIdx round-robin XCDs; give each XCD
        // contiguous nx-runs of one row-panel so its W+X working set fits 4MB L2.
        const int rows_per_xcd = gjs.j[ji].nblk / (8 * nx);
        const int xcd = bx & 7, pos = bx >> 3;
        by  = xcd * rows_per_xcd + pos / nx;
        bxx = pos % nx;
    } else {
        by = bx / nx; bxx = bx - by * nx;
    }
    const int bm = by * 128, bn = bxx * 128;

    const int lane = tid & 63, wave = tid >> 6;
    const int quad = lane >> 4, l16 = lane & 15;
    const int wm = wave >> 1, wn = wave & 1;

    f32x4 acc[4][4];
    #pragma unroll
    for (int i = 0; i < 4; ++i)
        #pragma unroll
        for (int j = 0; j < 4; ++j)
            acc[i][j] = (f32x4){0.f, 0.f, 0.f, 0.f};

    const int crow = tid >> 3;
    const int cko  = ((tid & 7) ^ (crow & 7)) * 8;
    int px[2];
    px[0] = ((quad) ^ (l16 & 7)) * 8;
    px[1] = ((4 + quad) ^ (l16 & 7)) * 8;

    const ushortT* gX = X + (size_t)(bm + crow) * K + cko;
    const ushortT* gW = Wt + (size_t)(bn + crow) * K + cko;

    for (int k0 = 0; k0 < K; k0 += 64) {
        __syncthreads();
        #pragma unroll
        for (int i = 0; i < 4; ++i) {
            const int s = tid + i * 256;
            ld_g2l16(gX + (size_t)(i * 32) * K + k0, &At[s * 8]);
            ld_g2l16(gW + (size_t)(i * 32) * K + k0, &Bt[s * 8]);
        }
        __syncthreads();

        #pragma unroll
        for (int kc = 0; kc < 2; ++kc) {
            bf16x8 af[4], bf[4];
            #pragma unroll
            for (int mt = 0; mt < 4; ++mt)
                af[mt] = *(const bf16x8*)&At[(wm * 64 + mt * 16 + l16) * 64 + px[kc]];
            #pragma unroll
            for (int nt = 0; nt < 4; ++nt)
                bf[nt] = *(const bf16x8*)&Bt[(wn * 64 + nt * 16 + l16) * 64 + px[kc]];
            #pragma unroll
            for (int mt = 0; mt < 4; ++mt)
                #pragma unroll
                for (int nt = 0; nt < 4; ++nt)
                    acc[mt][nt] = __builtin_amdgcn_mfma_f32_16x16x32_bf16(af[mt], bf[nt], acc[mt][nt], 0, 0, 0);
        }
    }

    const int row0 = bm + wm * 64, col0 = bn + wn * 64;
    if ((flags & 4) && bn >= D2_) {
        const int bb = row0 >> 9, s0 = row0 & 511;
        #pragma unroll
        for (int mt = 0; mt < 4; ++mt) {
            #pragma unroll
            for (int nt = 0; nt < 4; ++nt) {
                const int col = col0 + nt * 16 + l16;        // 1536..2303
                const int cv = col - D2_;
                const int hh = cv >> 6, dd = cv & 63;
                const float bval = bias[col];
                ushortT* vp = Yv + ((size_t)(bb * H_ + hh) * DH_ + dd) * S_
                                 + s0 + mt * 16 + quad * 4;
                uint2 u = make_uint2(pkbf(acc[mt][nt][0] + bval, acc[mt][nt][1] + bval),
                                     pkbf(acc[mt][nt][2] + bval, acc[mt][nt][3] + bval));
                *(uint2*)vp = u;
            }
        }
    } else {
        #pragma unroll
        for (int mt = 0; mt < 4; ++mt) {
            #pragma unroll
            for (int nt = 0; nt < 4; ++nt) {
                const int col = col0 + nt * 16 + l16;
                const float bval = (flags & 2) ? bias[col] : 0.f;
                #pragma unroll
                for (int r = 0; r < 4; ++r) {
                    const int row = row0 + mt * 16 + quad * 4 + r;
                    float vsum = acc[mt][nt][r] + bval;
                    if (flags & 1) ((float*)Y)[(size_t)row * ldy + col] = vsum;
                    else           ((ushortT*)Y)[(size_t)row * ldy + col] = f2bf(vsum);
                }
            }
        }
    }
}

// ---------------- MFMA flash attention (transposed, no-max softmax, swizzled LDS) ------
__global__ __launch_bounds__(256) void attn_mfma(
    const ushortT* __restrict__ qkP, const ushortT* __restrict__ qkM,
    const ushortT* __restrict__ vtP, const ushortT* __restrict__ vtM,
    ushortT* __restrict__ catP, ushortT* __restrict__ catM)
{
    __shared__ __attribute__((aligned(16))) ushortT Kt0[64 * 32], Kt1[64 * 32];
    __shared__ __attribute__((aligned(16))) ushortT Vt0[64 * 32], Vt1[64 * 32];
    __shared__ __attribute__((aligned(16))) ushortT Pt0[4][32 * 32], Pt1[4][32 * 32];

    const int tid = threadIdx.x;
    const int lane = tid & 63, wave = tid >> 6;
    const int quad = lane >> 4, l16 = lane & 15;
    const int bh = blockIdx.y, b = bh / H_, h = bh % H_;
    const int q0w = blockIdx.x * 128 + wave * 32;

    const ushortT *Q, *Kp, *Vp;
    ushortT* Out;
    int colbase;
    switch (blockIdx.z) {
        case 0:  Q = qkP; Kp = qkP + D_; Vp = vtP; Out = catP; colbase = 0;  break;
        case 1:  Q = qkM; Kp = qkP + D_; Vp = vtP; Out = catP; colbase = D_; break;
        case 2:  Q = qkM; Kp = qkM + D_; Vp = vtM; Out = catM; colbase = 0;  break;
        default: Q = qkP; Kp = qkM + D_; Vp = vtM; Out = catM; colbase = D_; break;
    }

    bf16x8 Qf[2][2];
    #pragma unroll
    for (int mt = 0; mt < 2; ++mt)
        #pragma unroll
        for (int kc = 0; kc < 2; ++kc)
            Qf[mt][kc] = *(const bf16x8*)(Q + (size_t)(b * S_ + q0w + mt * 16 + l16) * D2_
                                            + h * DH_ + kc * 32 + quad * 8);

    f32x4 OT[4][2];
    #pragma unroll
    for (int dt = 0; dt < 4; ++dt)
        #pragma unroll
        for (int mt = 0; mt < 2; ++mt)
            OT[dt][mt] = (f32x4){0.f, 0.f, 0.f, 0.f};
    float lrun[2] = {0.f, 0.f};

    const int drow = tid >> 2;
    const int dcl  = ((tid & 3) ^ ((drow >> 1) & 3)) * 8;
    const ushortT* gK = Kp + (size_t)(b * S_) * D2_ + h * DH_ + (size_t)drow * D2_ + dcl;
    const ushortT* gV = Vp + (size_t)bh * DH_ * S_ + (size_t)drow * S_ + dcl;

    const int swl = (l16 >> 1) & 3;
    const int rdo = (quad ^ swl) * 8;
    int roff[4];
    #pragma unroll
    for (int t = 0; t < 4; ++t) roff[t] = (t * 16 + l16) * 32 + rdo;
    int wpoff[2][2];
    #pragma unroll
    for (int mt = 0; mt < 2; ++mt)
        #pragma unroll
        for (int kb = 0; kb < 2; ++kb)
            wpoff[mt][kb] = (mt * 16 + l16) * 32 + (((kb * 2 + (quad >> 1)) ^ swl) * 8) + (quad & 1) * 4;

    for (int kt = 0; kt < S_; kt += 64) {
        __syncthreads();
        ld_g2l16(gK,      &Kt0[tid * 8]);
        ld_g2l16(gK + 32, &Kt1[tid * 8]);
        ld_g2l16(gV,      &Vt0[tid * 8]);
        ld_g2l16(gV + 32, &Vt1[tid * 8]);
        gK += (size_t)64 * D2_;
        gV += 64;
        __syncthreads();

        f32x4 St[4][2];
        #pragma unroll
        for (int ktl = 0; ktl < 4; ++ktl)
            #pragma unroll
            for (int mt = 0; mt < 2; ++mt)
                St[ktl][mt] = (f32x4){0.f, 0.f, 0.f, 0.f};
        #pragma unroll
        for (int ktl = 0; ktl < 4; ++ktl) {
            bf16x8 ka0 = *(const bf16x8*)&Kt0[roff[ktl]];
            bf16x8 ka1 = *(const bf16x8*)&Kt1[roff[ktl]];
            #pragma unroll
            for (int mt = 0; mt < 2; ++mt) {
                St[ktl][mt] = __builtin_amdgcn_mfma_f32_16x16x32_bf16(ka0, Qf[mt][0], St[ktl][mt], 0, 0, 0);
                St[ktl][mt] = __builtin_amdgcn_mfma_f32_16x16x32_bf16(ka1, Qf[mt][1], St[ktl][mt], 0, 0, 0);
            }
        }

        #pragma unroll
        for (int mt = 0; mt < 2; ++mt) {
            float rs = 0.f;
            #pragma unroll
            for (int ktl = 0; ktl < 4; ++ktl) {
                float p0 = EXP2(St[ktl][mt][0]);
                float p1 = EXP2(St[ktl][mt][1]);
                float p2 = EXP2(St[ktl][mt][2]);
                float p3 = EXP2(St[ktl][mt][3]);
                rs += (p0 + p1) + (p2 + p3);
                uint2 u = make_uint2(pkbf(p0, p1), pkbf(p2, p3));
                if (ktl < 2) *(uint2*)&Pt0[wave][wpoff[mt][ktl & 1]] = u;
                else         *(uint2*)&Pt1[wave][wpoff[mt][ktl & 1]] = u;
            }
            lrun[mt] += rs;
        }

        bf16x8 Pb[2][2];
        #pragma unroll
        for (int mt = 0; mt < 2; ++mt) {
            Pb[mt][0] = *(const bf16x8*)&Pt0[wave][(mt * 16 + l16) * 32 + rdo];
            Pb[mt][1] = *(const bf16x8*)&Pt1[wave][(mt * 16 + l16) * 32 + rdo];
        }
        #pragma unroll
        for (int dt = 0; dt < 4; ++dt) {
            bf16x8 va0 = *(const bf16x8*)&Vt0[roff[dt]];
            bf16x8 va1 = *(const bf16x8*)&Vt1[roff[dt]];
            #pragma unroll
            for (int mt = 0; mt < 2; ++mt) {
                OT[dt][mt] = __builtin_amdgcn_mfma_f32_16x16x32_bf16(va0, Pb[mt][0], OT[dt][mt], 0, 0, 0);
                OT[dt][mt] = __builtin_amdgcn_mfma_f32_16x16x32_bf16(va1, Pb[mt][1], OT[dt][mt], 0, 0, 0);
            }
        }
    }

    #pragma unroll
    for (int mt = 0; mt < 2; ++mt) {
        float l = lrun[mt];
        l += __shfl_xor(l, 16, 64);
        l += __shfl_xor(l, 32, 64);
        const float inv = 1.f / l;
        ushortT* yp = Out + (size_t)(b * S_ + q0w + mt * 16 + l16) * D2_ + colbase + h * DH_;
        #pragma unroll
        for (int dt = 0; dt < 4; ++dt) {
            uint2 u = make_uint2(pkbf(OT[dt][mt][0] * inv, OT[dt][mt][1] * inv),
                                 pkbf(OT[dt][mt][2] * inv, OT[dt][mt][3] * inv));
            *(uint2*)(yp + dt * 16 + quad * 4) = u;
        }
    }
}

// ---------------- launch ----------------
extern "C" void kernel_launch(void* const* d_in, const int* in_sizes, int n_in,
                              void* d_out, int out_size, void* d_ws, size_t ws_size,
                              hipStream_t stream) {
    const float* hs   = (const float*)d_in[0];
    const float* mol  = (const float*)d_in[1];
    const float* Wq   = (const float*)d_in[2];
    const float* bq   = (const float*)d_in[3];
    const float* Wk   = (const float*)d_in[4];
    const float* bk   = (const float*)d_in[5];
    const float* Wv   = (const float*)d_in[6];
    const float* bv   = (const float*)d_in[7];
    const float* Wqm  = (const float*)d_in[8];
    const float* bqm  = (const float*)d_in[9];
    const float* Wkm  = (const float*)d_in[10];
    const float* bkm  = (const float*)d_in[11];
    const float* Wvm  = (const float*)d_in[12];
    const float* bvm  = (const float*)d_in[13];
    const float* Wfc  = (const float*)d_in[14];
    const float* bfc  = (const float*)d_in[15];
    const float* Wfcm = (const float*)d_in[16];
    const float* bfcm = (const float*)d_in[17];
    const float* Wo   = (const float*)d_in[18];
    const float* bo   = (const float*)d_in[19];
    const float* Wom  = (const float*)d_in[20];
    const float* bom  = (const float*)d_in[21];

    float* out = (float*)d_out;
    ushortT* ws = (ushortT*)d_ws;

    ushortT* hsb   = ws;
    ushortT* molb  = hsb + ND_;
    ushortT* Wfcb  = molb + ND_;
    ushortT* Wfcmb = Wfcb + FSZ_;
    ushortT* WqT   = Wfcmb + FSZ_;     // prot stack: WqT|WkT|WvT contiguous
    ushortT* WkT   = WqT + WSZ_;
    ushortT* WvT   = WkT + WSZ_;
    ushortT* WqmT  = WvT + WSZ_;       // mol stack: WqmT|WkmT|WvmT contiguous
    ushortT* WkmT  = WqmT + WSZ_;
    ushortT* WvmT  = WkmT + WSZ_;
    ushortT* WoT   = WvmT + WSZ_;
    ushortT* WomT  = WoT + WSZ_;
    ushortT* WcoT  = WomT + WSZ_;
    ushortT* WcomT = WcoT + FSZ_;
    ushortT* qkP   = WcomT + FSZ_;     // [4096][1536]  (q | k)
    ushortT* qkM   = qkP + 2 * ND_;
    ushortT* vtrP  = qkM + 2 * ND_;    // [96][64][512]
    ushortT* vtrM  = vtrP + ND_;
    ushortT* catP  = vtrM + ND_;       // [4096][1536]
    ushortT* catM  = catP + 2 * ND_;
    float*   bcoP  = (float*)(catM + 2 * ND_);
    float*   bcoM  = bcoP + D_;
    float*   bqkvP = bcoM + D_;        // [2304] pre-scaled
    float*   bqkvM = bqkvP + D3_;

    // 1) prep
    {
        PrepJob pj;
        pj.hs = hs; pj.mol = mol; pj.Wfc = Wfc; pj.Wfcm = Wfcm;
        pj.hsb = hsb; pj.molb = molb; pj.Wfcb = Wfcb; pj.Wfcmb = Wfcmb;
        const float* wi[8] = {Wq, Wk, Wv, Wqm, Wkm, Wvm, Wo, Wom};
        ushortT* wo_[8]    = {WqT, WkT, WvT, WqmT, WkmT, WvmT, WoT, WomT};
        const float sc[8]  = {QSCL, 1.f, 1.f, QSCL, 1.f, 1.f, 1.f, 1.f};
        for (int i = 0; i < 8; ++i) { pj.tw_in[i] = wi[i]; pj.tw_out[i] = wo_[i]; pj.tw_scl[i] = sc[i]; }
        pj.bo = bo; pj.bom = bom;
        pj.bq = bq; pj.bk = bk; pj.bv = bv; pj.bqm = bqm; pj.bkm = bkm; pj.bvm = bvm;
        pj.bcoP = bcoP; pj.bcoM = bcoM; pj.bqkvP = bqkvP; pj.bqkvM = bqkvM;
        prep_k<<<dim3(PREP_NBLK), 256, 0, stream>>>(pj);
    }

    FoldArgs fa = {bfc, Wo, bfcm, Wom, bcoP, bcoM};

    // 2) gemm1: stacked QKV (XCD-remapped) + 2 weight folds + 32 bco-fold blocks
    {
        GJobs gj = {};
        gj.j[0] = {hsb,  WqT,  bqkvP,  qkP,   vtrP, 18, 576, D2_, 2 | 4 | 8};
        gj.j[1] = {molb, WqmT, bqkvM,  qkM,   vtrM, 18, 576, D2_, 2 | 4 | 8};
        gj.j[2] = {WoT,  Wfcb,  nullptr, WcoT,  nullptr, 12, 72, D2_, 0};
        gj.j[3] = {WomT, Wfcmb, nullptr, WcomT, nullptr, 12, 72, D2_, 0};
        const int total = 576 + 576 + 72 + 72;    // 1296
        gemm_flat<<<dim3(total + 32), 256, 0, stream>>>(gj, fa, D_, total);
    }

    // 3) four flash attentions -> concat buffers
    attn_mfma<<<dim3(S_ / 128, B_ * H_, 4), 256, 0, stream>>>(qkP, qkM, vtrP, vtrM, catP, catM);

    // 4) combined output GEMMs (K=1536, bias=bco, fp32 out) — round-8 known-good path
    {
        GJobs gj = {};
        gj.j[0] = {catP, WcoT,  bcoP, out,       nullptr, 6, 192, D_, 3};
        gj.j[1] = {catM, WcomT, bcoM, out + ND_, nullptr, 6, 192, D_, 3};
        gj.j[2].nblk = 0x7fffffff; gj.j[3].nblk = 0x7fffffff;
        gemm_flat<<<dim3(384), 256, 0, stream>>>(gj, fa, D2_, 384);
    }
}